// Round 1
// baseline (165.428 us; speedup 1.0000x reference)
//
#include <hip/hip_runtime.h>

typedef unsigned short ushort_t;
using short8 = __attribute__((ext_vector_type(8))) short;
using f32x4  = __attribute__((ext_vector_type(4))) float;

#define AS1 __attribute__((address_space(1)))
#define AS3 __attribute__((address_space(3)))

// Sizes (fixed by the problem)
#define B_   8
#define S_   2048
#define D_   1024
#define NIN  (8UL * 2048UL * 1024UL)   // 16,777,216 input elements

__device__ __forceinline__ ushort_t f2bf(float f) {
    unsigned u = __float_as_uint(f);
    u += 0x7FFFu + ((u >> 16) & 1u);   // round-to-nearest-even (inputs are finite normals)
    return (ushort_t)(u >> 16);
}

// ---------------- kernel 1: f32 -> bf16 bits (into d_out scratch region) ----------------
__global__ __launch_bounds__(256) void cvt_kernel(const float* __restrict__ in,
                                                  ushort_t* __restrict__ ob) {
    size_t i = ((size_t)blockIdx.x * 256 + threadIdx.x) * 8;
    const float4* p = (const float4*)(in + i);
    float4 a = p[0], c = p[1];
    short8 r;
    r[0] = (short)f2bf(a.x); r[1] = (short)f2bf(a.y);
    r[2] = (short)f2bf(a.z); r[3] = (short)f2bf(a.w);
    r[4] = (short)f2bf(c.x); r[5] = (short)f2bf(c.y);
    r[6] = (short)f2bf(c.z); r[7] = (short)f2bf(c.w);
    *(short8*)(ob + i) = r;
}

// ---------------- kernel 2: per-batch S = X X^T * (1/2048), bf16 MFMA ----------------
// 128x128 tile, BK=64, 4 waves (2x2), each wave 64x64 (4x4 frags of 16x16x32).
__global__ __launch_bounds__(256) void gemm_xxt(const ushort_t* __restrict__ X,
                                                float* __restrict__ S) {
    __shared__ __align__(16) ushort_t sA[128 * 64];
    __shared__ __align__(16) ushort_t sB[128 * 64];

    const int b = blockIdx.z;
    const ushort_t* Xb = X + (size_t)b * (S_ * D_);
    float* Sb = S + (size_t)b * (S_ * S_);

    const int tr = blockIdx.y * 128;
    const int tc = blockIdx.x * 128;
    const int tid  = threadIdx.x;
    const int lane = tid & 63;
    const int wid  = tid >> 6;
    const int wr = (wid >> 1) * 64;   // wave row offset in tile
    const int wc = (wid & 1) * 64;    // wave col offset in tile

    f32x4 acc[4][4] = {};

    const int srow = tid >> 3;        // 0..31: row within 32-row staging stripe
    const int scol = (tid & 7) * 8;   // element col within BK
    const int rsel = lane & 15;
    const int ksel = (lane >> 4) * 8;

    for (int kt = 0; kt < D_ / 64; ++kt) {
        const int k0 = kt * 64;
        if (kt) __syncthreads();      // all waves done reading previous tile
#pragma unroll
        for (int c = 0; c < 4; ++c) {
            const ushort_t* gA = Xb + (size_t)(tr + c * 32 + srow) * D_ + k0 + scol;
            const ushort_t* gB = Xb + (size_t)(tc + c * 32 + srow) * D_ + k0 + scol;
            __builtin_amdgcn_global_load_lds((const AS1 void*)gA,
                                             (AS3 void*)(sA + c * 2048 + tid * 8), 16, 0, 0);
            __builtin_amdgcn_global_load_lds((const AS1 void*)gB,
                                             (AS3 void*)(sB + c * 2048 + tid * 8), 16, 0, 0);
        }
        __syncthreads();              // implies s_waitcnt vmcnt(0) before barrier

#pragma unroll
        for (int kk = 0; kk < 2; ++kk) {
            const int kb = kk * 32 + ksel;
            short8 af[4], bf[4];
#pragma unroll
            for (int m = 0; m < 4; ++m)
                af[m] = *(const short8*)&sA[(wr + m * 16 + rsel) * 64 + kb];
#pragma unroll
            for (int n = 0; n < 4; ++n)
                bf[n] = *(const short8*)&sB[(wc + n * 16 + rsel) * 64 + kb];
#pragma unroll
            for (int m = 0; m < 4; ++m) {
#pragma unroll
                for (int n = 0; n < 4; ++n) {
                    acc[m][n] = __builtin_amdgcn_mfma_f32_16x16x32_bf16(
                        af[m], bf[n], acc[m][n], 0, 0, 0);
                }
            }
        }
    }

    // epilogue: scale by 1/seq_len, write f32 logits
    const float scale = 1.0f / 2048.0f;
    const int r0 = (lane >> 4) * 4;
    const int c0 = lane & 15;
#pragma unroll
    for (int m = 0; m < 4; ++m) {
#pragma unroll
        for (int n = 0; n < 4; ++n) {
            float* dst = Sb + (size_t)(tr + wr + m * 16 + r0) * S_ + (tc + wc + n * 16 + c0);
#pragma unroll
            for (int r = 0; r < 4; ++r)
                dst[(size_t)r * S_] = acc[m][n][r] * scale;
        }
    }
}

// ---------------- kernel 3: row softmax in-place, one wave per row ----------------
__global__ __launch_bounds__(256) void softmax_rows(float* __restrict__ S) {
    const int row  = blockIdx.x * 4 + (threadIdx.x >> 6);
    const int lane = threadIdx.x & 63;
    float4* p = (float4*)(S + (size_t)row * S_);

    float4 v[8];
    float mx = -3.0e38f;
#pragma unroll
    for (int i = 0; i < 8; ++i) {
        v[i] = p[i * 64 + lane];
        mx = fmaxf(mx, fmaxf(fmaxf(v[i].x, v[i].y), fmaxf(v[i].z, v[i].w)));
    }
#pragma unroll
    for (int o = 32; o > 0; o >>= 1) mx = fmaxf(mx, __shfl_xor(mx, o, 64));

    float sum = 0.0f;
#pragma unroll
    for (int i = 0; i < 8; ++i) {
        v[i].x = __expf(v[i].x - mx);
        v[i].y = __expf(v[i].y - mx);
        v[i].z = __expf(v[i].z - mx);
        v[i].w = __expf(v[i].w - mx);
        sum += (v[i].x + v[i].y) + (v[i].z + v[i].w);
    }
#pragma unroll
    for (int o = 32; o > 0; o >>= 1) sum += __shfl_xor(sum, o, 64);

    const float rs = 1.0f / sum;
#pragma unroll
    for (int i = 0; i < 8; ++i) {
        v[i].x *= rs; v[i].y *= rs; v[i].z *= rs; v[i].w *= rs;
        p[i * 64 + lane] = v[i];
    }
}

// ---------------- kernel 4: exact f32 copy of inputs into output slot 0 ----------------
__global__ __launch_bounds__(256) void copy_kernel(const float4* __restrict__ in,
                                                   float4* __restrict__ out) {
    size_t i = (size_t)blockIdx.x * 256 + threadIdx.x;
    out[i] = in[i];
}

extern "C" void kernel_launch(void* const* d_in, const int* in_sizes, int n_in,
                              void* d_out, int out_size, void* d_ws, size_t ws_size,
                              hipStream_t stream) {
    const float* X   = (const float*)d_in[0];
    float* out       = (float*)d_out;
    float* scores    = out + NIN;                 // second output region
    ushort_t* xbf    = (ushort_t*)d_out;          // park bf16 X in output slot 0 (33.5MB of 67MB)

    // 1. convert inputs to bf16 (scratch in out[0] region)
    cvt_kernel<<<NIN / (256 * 8), 256, 0, stream>>>(X, xbf);

    // 2. batched S = X X^T / 2048 (bf16 MFMA, f32 logits)
    dim3 g(S_ / 128, S_ / 128, B_);
    gemm_xxt<<<g, 256, 0, stream>>>(xbf, scores);

    // 3. row softmax in-place
    softmax_rows<<<(B_ * S_) / 4, 256, 0, stream>>>(scores);

    // 4. restore output slot 0 with the exact f32 inputs
    copy_kernel<<<NIN / (256 * 4), 256, 0, stream>>>((const float4*)X, (float4*)out);
}